// Round 5
// baseline (566.311 us; speedup 1.0000x reference)
//
#include <hip/hip_runtime.h>
#include <cstdint>
#include <cstddef>

typedef float floatx4 __attribute__((ext_vector_type(4)));
typedef short bf16x8 __attribute__((ext_vector_type(8)));

#define MFMA(a, b, c) __builtin_amdgcn_mfma_f32_16x16x32_bf16((a), (b), (c), 0, 0, 0)

__device__ __forceinline__ unsigned short f2bf(float f) {
  union { float f; unsigned int u; } v; v.f = f;
  unsigned int u = v.u;
  unsigned int r = (u + 0x7FFFu + ((u >> 16) & 1u)) >> 16;
  return (unsigned short)r;
}

__device__ __forceinline__ void gload_lds16(const unsigned short* g, unsigned short* s) {
  __builtin_amdgcn_global_load_lds(
      (const __attribute__((address_space(1))) unsigned int*)g,
      (__attribute__((address_space(3))) unsigned int*)s, 16, 0, 0);
}

// ------------------------------------------------------------------
// Tiled transpose + fp32->bf16 cast: src [R,C] fp32 -> dst [C,R] bf16,
// dst row stride ldd.  grid (C/32, R/32)
// ------------------------------------------------------------------
__global__ __launch_bounds__(256) void transpose_cast(
    const float* __restrict__ src, unsigned short* __restrict__ dst,
    int R, int C, int ldd) {
  __shared__ float tile[32][33];
  int bx = blockIdx.x, by = blockIdx.y;
  int tx = threadIdx.x & 31, ty = threadIdx.x >> 5;
#pragma unroll
  for (int i = 0; i < 4; i++) {
    int r = ty + i * 8;
    tile[r][tx] = src[(size_t)(by * 32 + r) * C + bx * 32 + tx];
  }
  __syncthreads();
#pragma unroll
  for (int i = 0; i < 4; i++) {
    int r = ty + i * 8;
    dst[(size_t)(bx * 32 + r) * ldd + by * 32 + tx] = f2bf(tile[tx][r]);
  }
}

// ------------------------------------------------------------------
// RMSNorm: x [8192,1024] fp32 -> xn bf16.  One block per row.
// ------------------------------------------------------------------
__global__ __launch_bounds__(256) void rmsnorm_kernel(
    const float* __restrict__ x, const float* __restrict__ scale,
    unsigned short* __restrict__ xn) {
  int row = blockIdx.x;
  const float4 v = ((const float4*)(x + (size_t)row * 1024))[threadIdx.x];
  float ss = v.x * v.x + v.y * v.y + v.z * v.z + v.w * v.w;
#pragma unroll
  for (int off = 1; off < 64; off <<= 1) ss += __shfl_xor(ss, off, 64);
  __shared__ float ws4[4];
  if ((threadIdx.x & 63) == 0) ws4[threadIdx.x >> 6] = ss;
  __syncthreads();
  float tot = ws4[0] + ws4[1] + ws4[2] + ws4[3];
  float rs = rsqrtf(tot * (1.0f / 1024.0f) + 1e-6f);
  const float4 sc = ((const float4*)scale)[threadIdx.x];
  uint2 o;
  o.x = (unsigned)f2bf(v.x * rs * sc.x) | ((unsigned)f2bf(v.y * rs * sc.y) << 16);
  o.y = (unsigned)f2bf(v.z * rs * sc.z) | ((unsigned)f2bf(v.w * rs * sc.w) << 16);
  ((uint2*)(xn + (size_t)row * 1024))[threadIdx.x] = o;
}

// ------------------------------------------------------------------
// GEMM: C[M,N] = A[M,K] * BT[N,K]^T (both bf16, K-major).  128x128
// tile, BK=32 DOUBLE-BUFFERED with zero-register prefetch: next
// tile's global_load_lds issues BEFORE compute on current, so the
// vmcnt(0) drain at the barrier lands after ~600cyc of MFMA work.
// One __syncthreads per 32-k.  XCD swizzle: id%8 -> (M,N)-region.
// MODE 6 (fused input): col<4096 gelu->cat[row*5120+col];
//   else q*0.125 / k scatter [B,H,S,HD], v -> [B,H,HD,S]
// MODE 7 (fused output): out[row*1024+col]=v+b1[col]+b2[col]+resid
// ------------------------------------------------------------------
template <int MODE>
__global__ __launch_bounds__(256, 2) void gemm_bt(
    const unsigned short* __restrict__ A, const unsigned short* __restrict__ BT,
    int K, void* __restrict__ outp,
    const float* __restrict__ bias1, const float* __restrict__ bias2,
    const float* __restrict__ resid,
    int msplit, int tm, int tn,
    unsigned short* __restrict__ q_out, unsigned short* __restrict__ k_out,
    unsigned short* __restrict__ v_out) {
  __shared__ unsigned short As[2][128 * 32];
  __shared__ unsigned short Bs[2][128 * 32];

  int id = blockIdx.x + gridDim.x * blockIdx.y;
  int xcd = id & 7, j = id >> 3;
  int mh = xcd % msplit, nq = xcd / msplit;
  int by = mh * tm + j / tn;
  int bx = nq * tn + j % tn;
  int m0 = by * 128, n0 = bx * 128;

  int t = threadIdx.x, lane = t & 63, wave = t >> 6;
  int l15 = lane & 15, quad = lane >> 4;
  int wm = (wave & 1) * 64, wn = (wave >> 1) * 64;

  floatx4 acc[4][4] = {};

  // staging: per wave two 1KB chunks per buffer (16 rows x 32 shorts)
  int off0 = wave * 1024 + lane * 8;
  int off1 = off0 + 512;
  int r0 = off0 >> 5, c0 = off0 & 31;
  const unsigned short* gA0 = A + (size_t)(m0 + r0) * K + c0;
  const unsigned short* gA1 = A + (size_t)(m0 + r0 + 16) * K + c0;
  const unsigned short* gB0 = BT + (size_t)(n0 + r0) * K + c0;
  const unsigned short* gB1 = BT + (size_t)(n0 + r0 + 16) * K + c0;
  unsigned short* sA0[2] = {&As[0][off0], &As[1][off0]};
  unsigned short* sA1[2] = {&As[0][off1], &As[1][off1]};
  unsigned short* sB0[2] = {&Bs[0][off0], &Bs[1][off0]};
  unsigned short* sB1[2] = {&Bs[0][off1], &Bs[1][off1]};

  // prologue: stage k-chunk 0 into buffer 0
  gload_lds16(gA0, sA0[0]);
  gload_lds16(gA1, sA1[0]);
  gload_lds16(gB0, sB0[0]);
  gload_lds16(gB1, sB1[0]);

  int nIter = K >> 5;
  for (int it = 0; it < nIter; it++) {
    int p = it & 1;
    __syncthreads();  // drains buf-p loads (issued last iter, after its MFMAs)
    if (it + 1 < nIter) {
      int kn = (it + 1) << 5;
      int q = p ^ 1;
      gload_lds16(gA0 + kn, sA0[q]);
      gload_lds16(gA1 + kn, sA1[q]);
      gload_lds16(gB0 + kn, sB0[q]);
      gload_lds16(gB1 + kn, sB1[q]);
    }
    bf16x8 a[4], b[4];
#pragma unroll
    for (int im = 0; im < 4; im++)
      a[im] = *(const bf16x8*)&As[p][(wm + im * 16 + l15) * 32 + quad * 8];
#pragma unroll
    for (int in_ = 0; in_ < 4; in_++)
      b[in_] = *(const bf16x8*)&Bs[p][(wn + in_ * 16 + l15) * 32 + quad * 8];
#pragma unroll
    for (int im = 0; im < 4; im++)
#pragma unroll
      for (int in_ = 0; in_ < 4; in_++)
        acc[im][in_] = MFMA(a[im], b[in_], acc[im][in_]);
  }

#pragma unroll
  for (int im = 0; im < 4; im++) {
#pragma unroll
    for (int in_ = 0; in_ < 4; in_++) {
#pragma unroll
      for (int r = 0; r < 4; r++) {
        int row = m0 + wm + im * 16 + quad * 4 + r;
        int col = n0 + wn + in_ * 16 + l15;
        float v = acc[im][in_][r];
        if constexpr (MODE == 6) {
          if (n0 < 4096) {
            float z = 0.7978845608028654f * (v + 0.044715f * v * v * v);
            float e = __expf(2.0f * z);
            float th = 1.0f - 2.0f / (e + 1.0f);
            ((unsigned short*)outp)[(size_t)row * 5120 + col] = f2bf(0.5f * v * (1.0f + th));
          } else {
            int seg = (n0 - 4096) >> 10;          // 0=q 1=k 2=v (tile-uniform)
            int cs = col - 4096 - (seg << 10);
            int b_ = row >> 11, s = row & 2047, h = cs >> 6, hd = cs & 63;
            if (seg == 0)
              q_out[(((size_t)(b_ * 16 + h)) * 2048 + s) * 64 + hd] = f2bf(v * 0.125f);
            else if (seg == 1)
              k_out[(((size_t)(b_ * 16 + h)) * 2048 + s) * 64 + hd] = f2bf(v);
            else
              v_out[(((size_t)(b_ * 16 + h)) * 64 + hd) * 2048 + s] = f2bf(v);
          }
        } else {
          size_t idx = (size_t)row * 1024 + col;
          ((float*)outp)[idx] = v + bias1[col] + bias2[col] + resid[idx];
        }
      }
    }
  }
}

// ------------------------------------------------------------------
// Flash attention, no-max additive variant.  q pre-scaled by 0.125.
// q,k [B,H,S,HD]; v [B,H,HD,S] bf16.  av -> cat cols 4096..5120.
// 4 waves x 32 q rows; kv tile 64.  Register-prefetch of next K/V
// tile issued right after staging barrier; Ps visibility via
// s_waitcnt lgkmcnt(0) (per-wave LDS, no barrier -> no vmcnt drain).
// ------------------------------------------------------------------
__global__ __launch_bounds__(256, 2) void flash_attn(
    const unsigned short* __restrict__ q_buf, const unsigned short* __restrict__ k_buf,
    const unsigned short* __restrict__ v_buf, unsigned short* __restrict__ cat) {
  constexpr int S = 2048, HD = 64;
  constexpr int LK = 72, LV = 72, LP = 68;
  __shared__ unsigned short Ks[64 * LK];
  __shared__ unsigned short Vs[64 * LV];
  __shared__ unsigned short Ps[4][32 * LP];

  int id = blockIdx.x + gridDim.x * blockIdx.y;   // grid (16, 64)
  int xcd = id & 7, j = id >> 3;                  // j in [0,128)
  int bh = xcd * 8 + (j >> 4);
  int qbk = j & 15;

  int t = threadIdx.x, lane = t & 63, wave = t >> 6;
  int l15 = lane & 15, quad = lane >> 4;

  const unsigned short* qp = q_buf + (size_t)bh * S * HD;
  const unsigned short* kp = k_buf + (size_t)bh * S * HD;
  const unsigned short* vp = v_buf + (size_t)bh * HD * S;

  int q0 = qbk * 128 + wave * 32;
  bf16x8 aQ[2][2];
#pragma unroll
  for (int qf = 0; qf < 2; qf++) {
    aQ[qf][0] = *(const bf16x8*)&qp[(size_t)(q0 + qf * 16 + l15) * HD + quad * 8];
    aQ[qf][1] = *(const bf16x8*)&qp[(size_t)(q0 + qf * 16 + l15) * HD + 32 + quad * 8];
  }

  floatx4 acc_o[2][4] = {};
  float lrow[2][4] = {};

  int kr = t >> 3, kc = (t & 7) * 8;

  // register prefetch of K/V tile (2 rows each)
  uint4 rK0 = *(const uint4*)&kp[(size_t)kr * HD + kc];
  uint4 rK1 = *(const uint4*)&kp[(size_t)(kr + 32) * HD + kc];
  uint4 rV0 = *(const uint4*)&vp[(size_t)kr * S + kc];
  uint4 rV1 = *(const uint4*)&vp[(size_t)(kr + 32) * S + kc];

  for (int kv = 0; kv < S; kv += 64) {
    __syncthreads();  // prev tile's LDS reads done; prefetch regs ready
    *(uint4*)&Ks[kr * LK + kc] = rK0;
    *(uint4*)&Ks[(kr + 32) * LK + kc] = rK1;
    *(uint4*)&Vs[kr * LV + kc] = rV0;
    *(uint4*)&Vs[(kr + 32) * LV + kc] = rV1;
    __syncthreads();  // Ks/Vs visible (nothing outstanding in vmem here)
    if (kv + 64 < S) {  // issue next-tile loads; drained at next top barrier
      rK0 = *(const uint4*)&kp[(size_t)(kv + 64 + kr) * HD + kc];
      rK1 = *(const uint4*)&kp[(size_t)(kv + 64 + kr + 32) * HD + kc];
      rV0 = *(const uint4*)&vp[(size_t)kr * S + kv + 64 + kc];
      rV1 = *(const uint4*)&vp[(size_t)(kr + 32) * S + kv + 64 + kc];
    }

    floatx4 z[2][4];
#pragma unroll
    for (int cg = 0; cg < 4; cg++) {
      bf16x8 bk0 = *(const bf16x8*)&Ks[(cg * 16 + l15) * LK + quad * 8];
      bf16x8 bk1 = *(const bf16x8*)&Ks[(cg * 16 + l15) * LK + 32 + quad * 8];
#pragma unroll
      for (int qf = 0; qf < 2; qf++) {
        floatx4 acc = {};
        acc = MFMA(aQ[qf][0], bk0, acc);
        acc = MFMA(aQ[qf][1], bk1, acc);
        z[qf][cg] = acc;
      }
    }
#pragma unroll
    for (int qf = 0; qf < 2; qf++)
#pragma unroll
      for (int cg = 0; cg < 4; cg++)
#pragma unroll
        for (int r = 0; r < 4; r++) {
          float e = __expf(z[qf][cg][r]);
          lrow[qf][r] += e;
          Ps[wave][(qf * 16 + quad * 4 + r) * LP + cg * 16 + l15] = f2bf(e);
        }
    // own-wave LDS visibility only: wait DS queue, NOT a barrier (keeps
    // the K/V prefetch in flight across the PV block)
    asm volatile("s_waitcnt lgkmcnt(0)" ::: "memory");
#pragma unroll
    for (int c = 0; c < 2; c++) {
      bf16x8 aP[2];
#pragma unroll
      for (int qf = 0; qf < 2; qf++) {
        const unsigned short* pp = &Ps[wave][(qf * 16 + l15) * LP + c * 32 + quad * 8];
        ((uint2*)&aP[qf])[0] = *(const uint2*)pp;
        ((uint2*)&aP[qf])[1] = *(const uint2*)(pp + 4);
      }
#pragma unroll
      for (int n = 0; n < 4; n++) {
        bf16x8 bv = *(const bf16x8*)&Vs[(n * 16 + l15) * LV + c * 32 + quad * 8];
        acc_o[0][n] = MFMA(aP[0], bv, acc_o[0][n]);
        acc_o[1][n] = MFMA(aP[1], bv, acc_o[1][n]);
      }
    }
  }

#pragma unroll
  for (int qf = 0; qf < 2; qf++)
#pragma unroll
    for (int r = 0; r < 4; r++) {
      float s = lrow[qf][r];
#pragma unroll
      for (int off = 1; off < 16; off <<= 1) s += __shfl_xor(s, off, 16);
      lrow[qf][r] = s;
    }

  int b_ = bh >> 4, h = bh & 15;
#pragma unroll
  for (int qf = 0; qf < 2; qf++)
#pragma unroll
    for (int r = 0; r < 4; r++) {
      float inv = 1.0f / lrow[qf][r];
      int srow = q0 + qf * 16 + quad * 4 + r;
      size_t base = ((size_t)(b_ * 2048 + srow)) * 5120 + 4096 + h * 64;
#pragma unroll
      for (int n = 0; n < 4; n++)
        cat[base + n * 16 + l15] = f2bf(acc_o[qf][n][r] * inv);
    }
}

// ------------------------------------------------------------------
extern "C" void kernel_launch(void* const* d_in, const int* in_sizes, int n_in,
                              void* d_out, int out_size, void* d_ws, size_t ws_size,
                              hipStream_t stream) {
  (void)in_sizes; (void)n_in; (void)out_size; (void)ws_size;
  const float* x          = (const float*)d_in[0];
  const float* pns        = (const float*)d_in[1];
  const float* w_mlp_in   = (const float*)d_in[2];
  const float* wq         = (const float*)d_in[3];
  const float* wk         = (const float*)d_in[4];
  const float* wv         = (const float*)d_in[5];
  const float* w_mlp_out  = (const float*)d_in[6];
  const float* b_mlp_out  = (const float*)d_in[7];
  const float* w_attn_out = (const float*)d_in[8];
  const float* b_attn_out = (const float*)d_in[9];
  float* out = (float*)d_out;

  char* ws = (char*)d_ws;
  size_t off = 0;
  auto alloc = [&](size_t bytes) {
    void* p = ws + off;
    off += (bytes + 255) & ~(size_t)255;
    return p;
  };
  const size_t M = 8192;
  unsigned short* xn     = (unsigned short*)alloc(M * 1024 * 2);
  unsigned short* wcatT  = (unsigned short*)alloc((size_t)7168 * 1024 * 2);  // [mlp_in|q|k|v][N,K]
  unsigned short* wcat2T = (unsigned short*)alloc((size_t)1024 * 5120 * 2);  // [N=1024, K=5120]
  unsigned short* cat    = (unsigned short*)alloc(M * 5120 * 2);             // [h | av]
  unsigned short* qb     = (unsigned short*)alloc(M * 1024 * 2);
  unsigned short* kb     = (unsigned short*)alloc(M * 1024 * 2);
  unsigned short* vb     = (unsigned short*)alloc(M * 1024 * 2);

  transpose_cast<<<dim3(128, 32), 256, 0, stream>>>(w_mlp_in, wcatT, 1024, 4096, 1024);
  transpose_cast<<<dim3(32, 32), 256, 0, stream>>>(wq, wcatT + (size_t)4096 * 1024, 1024, 1024, 1024);
  transpose_cast<<<dim3(32, 32), 256, 0, stream>>>(wk, wcatT + (size_t)5120 * 1024, 1024, 1024, 1024);
  transpose_cast<<<dim3(32, 32), 256, 0, stream>>>(wv, wcatT + (size_t)6144 * 1024, 1024, 1024, 1024);
  transpose_cast<<<dim3(32, 128), 256, 0, stream>>>(w_mlp_out, wcat2T, 4096, 1024, 5120);
  transpose_cast<<<dim3(32, 32), 256, 0, stream>>>(w_attn_out, wcat2T + 4096, 1024, 1024, 5120);

  rmsnorm_kernel<<<dim3(8192), 256, 0, stream>>>(x, pns, xn);

  // fused input GEMM: [8192,1024] x [7168,1024]^T; msplit=2 nsplit=4
  gemm_bt<6><<<dim3(56, 64), 256, 0, stream>>>(
      xn, wcatT, 1024, cat, nullptr, nullptr, nullptr, 2, 32, 14, qb, kb, vb);

  flash_attn<<<dim3(16, 64), 256, 0, stream>>>(qb, kb, vb, cat);

  // fused output GEMM: [8192,5120] x [1024,5120]^T; msplit=2 nsplit=4
  gemm_bt<7><<<dim3(8, 64), 256, 0, stream>>>(
      cat, wcat2T, 5120, out, b_mlp_out, b_attn_out, x, 2, 32, 2, nullptr, nullptr, nullptr);
}